// Round 3
// baseline (1036.004 us; speedup 1.0000x reference)
//
#include <hip/hip_runtime.h>

#define LRELU 0.2f
#define EPS_D 1e-8f

static constexpr int B = 8;
static constexpr int C = 512;
static constexpr int HO = 64, WO = 64;
static constexpr int HW = HO * WO;     // 4096
static constexpr int HIN = 32;

typedef _Float16 f16;
typedef _Float16 f16x8 __attribute__((ext_vector_type(8)));
typedef _Float16 f16x4 __attribute__((ext_vector_type(4)));
typedef float f32x4 __attribute__((ext_vector_type(4)));

// workspace byte offsets
static constexpr size_t XUP_B  = 0;                         // [B][64][64][512] f16
static constexpr size_t H1S_B  = 33554432;                  // [B][64][64][512] f16
static constexpr size_t WP1_B  = 67108864;                  // [9][512][512] f16
static constexpr size_t WP2_B  = 71827456;                  // [9][512][512] f16
static constexpr size_t S1_B   = 76546048;                  // [B][C] f32
static constexpr size_t S2_B   = S1_B + 16384;
static constexpr size_t SR_B   = S2_B + 16384;
static constexpr size_t D1_B   = SR_B + 16384;
static constexpr size_t D2_B   = D1_B + 16384;
static constexpr size_t WSQ1_B = D2_B + 16384;              // [C][C] f32
static constexpr size_t WSQ2_B = WSQ1_B + 1048576;

// ---------------------------------------------------------------------------
// styles x3 fused: s[b][i] = mod_b[i] + sum_j w[b][j] * mod_w[i][j]
// grid = (B, 3), 256 threads
__global__ void k_styles3(const float* __restrict__ wsty,
                          const float* __restrict__ mw0, const float* __restrict__ mb0, float* __restrict__ so0,
                          const float* __restrict__ mw1, const float* __restrict__ mb1, float* __restrict__ so1,
                          const float* __restrict__ mw2, const float* __restrict__ mb2, float* __restrict__ so2) {
  __shared__ float wsh[C];
  int b = blockIdx.x;
  int which = blockIdx.y;
  const float* mw = which == 0 ? mw0 : (which == 1 ? mw1 : mw2);
  const float* mb = which == 0 ? mb0 : (which == 1 ? mb1 : mb2);
  float* sout     = which == 0 ? so0 : (which == 1 ? so1 : so2);
  int t = threadIdx.x;
  wsh[t]       = wsty[b * C + t];
  wsh[t + 256] = wsty[b * C + t + 256];
  __syncthreads();
  for (int i = t; i < C; i += 256) {
    float acc = mb[i];
    const float* row = mw + (size_t)i * C;
#pragma unroll 4
    for (int j = 0; j < C; ++j) acc = fmaf(wsh[j], row[j], acc);
    sout[b * C + i] = acc;
  }
}

// ---------------------------------------------------------------------------
// weight prepack: W fp32 [co][ci][9] -> Wp f16 [tap][co][ci], plus
// wsq[co*C+ci] = sum_tap W^2 (for demod)
__global__ void k_packw(const float* __restrict__ w, f16* __restrict__ wp,
                        float* __restrict__ wsq) {
  int idx = blockIdx.x * 256 + threadIdx.x;   // co*512+ci
  const float* src = w + (size_t)idx * 9;
  float acc = 0.f;
#pragma unroll
  for (int tap = 0; tap < 9; ++tap) {
    float v = src[tap];
    wp[(size_t)tap * (C * C) + idx] = (f16)v;
    acc = fmaf(v, v, acc);
  }
  wsq[idx] = acc;
}

// ---------------------------------------------------------------------------
// demod: d[b][co] = rsqrt( sum_ci s[b][ci]^2 * wsq[co][ci] + eps )
// grid = C blocks, 256 threads
__global__ void k_demod(const float* __restrict__ wsq,  // [C][C]
                        const float* __restrict__ s,    // [B][C]
                        float* __restrict__ dout) {     // [B][C]
  __shared__ float ssq[B * C];
  __shared__ float red[4][B];
  int co = blockIdx.x;
  int t = threadIdx.x;
  for (int idx = t; idx < B * C; idx += 256) {
    float v = s[idx];
    ssq[idx] = v * v;
  }
  __syncthreads();
  int ci0 = t * 2;
  float w0 = wsq[(size_t)co * C + ci0];
  float w1 = wsq[(size_t)co * C + ci0 + 1];
  float p[B];
#pragma unroll
  for (int b = 0; b < B; ++b) {
    p[b] = fmaf(ssq[b * C + ci0], w0, ssq[b * C + ci0 + 1] * w1);
  }
  int lane = t & 63, wv = t >> 6;
#pragma unroll
  for (int b = 0; b < B; ++b) {
    float v = p[b];
    for (int off = 32; off; off >>= 1) v += __shfl_down(v, off);
    if (lane == 0) red[wv][b] = v;
  }
  __syncthreads();
  if (t < B) {
    float tot = red[0][t] + red[1][t] + red[2][t] + red[3][t];
    dout[t * C + co] = rsqrtf(tot + EPS_D);
  }
}

// ---------------------------------------------------------------------------
__device__ __forceinline__ void up1d(int o, int& i0, int& i1, float& w0, float& w1) {
  float src = 0.5f * (float)o - 0.25f;
  float f = floorf(src);
  float fr = src - f;
  int i = (int)f;
  i0 = i < 0 ? 0 : i;
  int j = i + 1;
  i1 = j > (HIN - 1) ? (HIN - 1) : j;
  w1 = fr;
  w0 = 1.0f - fr;
}

// bilinear 2x upsample + s1 scale, NCHW fp32 -> NHWC f16.
// grid = B * 16 (ci chunks of 32) * 4 (yo quarters), 256 threads, 20KB LDS
__global__ __launch_bounds__(256) void k_up(const float* __restrict__ x,
                                            const float* __restrict__ s1,
                                            f16* __restrict__ xup) {
  __shared__ f16 xt[10 * 32 * 32];  // [(yl*32+x)*32 + ci]
  int bx = blockIdx.x;
  int b = bx >> 6;
  int ci0 = ((bx >> 2) & 15) * 32;
  int q = bx & 3;
  int ybase = q * 8 - 1;            // src rows ybase..ybase+9 (clamped)
  int t = threadIdx.x;
  int xi_ = t & 31, cl = t >> 5;    // cl 0..7
  for (int yl = 0; yl < 10; ++yl) {
    int y = ybase + yl;
    y = y < 0 ? 0 : (y > 31 ? 31 : y);
#pragma unroll
    for (int p = 0; p < 4; ++p) {
      int ci = p * 8 + cl;
      xt[(yl * 32 + xi_) * 32 + ci] =
          (f16)x[(((size_t)b * C + ci0 + ci) * 32 + y) * 32 + xi_];
    }
  }
  __syncthreads();
  int xo = t >> 2;          // 0..63
  int cg = (t & 3) * 8;
  float sv[8];
#pragma unroll
  for (int e = 0; e < 8; ++e) sv[e] = s1[b * C + ci0 + cg + e];
  int x0, x1; float wx0, wx1;
  up1d(xo, x0, x1, wx0, wx1);
  for (int yy = 0; yy < 16; ++yy) {
    int yo = q * 16 + yy;
    int y0, y1; float wy0, wy1;
    up1d(yo, y0, y1, wy0, wy1);
    int yl0 = y0 - ybase, yl1 = y1 - ybase;
    f16x8 t00 = *(const f16x8*)&xt[(yl0 * 32 + x0) * 32 + cg];
    f16x8 t01 = *(const f16x8*)&xt[(yl0 * 32 + x1) * 32 + cg];
    f16x8 t10 = *(const f16x8*)&xt[(yl1 * 32 + x0) * 32 + cg];
    f16x8 t11 = *(const f16x8*)&xt[(yl1 * 32 + x1) * 32 + cg];
    f16x8 o;
#pragma unroll
    for (int e = 0; e < 8; ++e) {
      float v = wy0 * (wx0 * (float)t00[e] + wx1 * (float)t01[e]) +
                wy1 * (wx0 * (float)t10[e] + wx1 * (float)t11[e]);
      o[e] = (f16)(v * sv[e]);
    }
    *(f16x8*)&xup[(((size_t)b * 64 + yo) * 64 + xo) * C + ci0 + cg] = o;
  }
}

// ---------------------------------------------------------------------------
// MFMA implicit-GEMM 3x3 conv. Input NHWC f16 (style pre-applied), weights
// read DIRECTLY from global [tap][co][ci] f16 (L1/L2-served, broadcast across
// waves). Only the input tile is LDS-staged, XOR-swizzled to kill the
// stride-64B bank conflicts on the B-fragment ds_read_b128s.
// Block: 64 co x 256 px (4 rows x 64 cols), 4 waves, wave = 64co x 64px.
__global__ __launch_bounds__(256) void k_conv_mfma(
    const f16* __restrict__ xin,      // [B][64][64][C]
    const f16* __restrict__ Wp,       // [9][C][C]
    const float* __restrict__ dmod,   // [B][C]
    const float* __restrict__ nscale, // [C]
    const float* __restrict__ noise,  // [B][HW]
    const float* __restrict__ s2v,    // [B][C] (conv1 only)
    f16* __restrict__ out_nhwc,       // conv1 out or null
    float* __restrict__ out_nchw) {   // conv2 out or null
  __shared__ char xsb[6 * 66 * 64];   // swizzled: [pc][4 chunks of 16B]

  int bx = blockIdx.x;
  int b = bx >> 7;
  int rem = bx & 127;
  int co_base = (rem >> 4) * 64;
  int y0 = (rem & 15) * 4;
  int t = threadIdx.x;
  int lane = t & 63, wid = t >> 6;
  int ln = lane & 15, kg = lane >> 4;

  f32x4 acc[4][4] = {};

  for (int ck = 0; ck < 16; ++ck) {
    __syncthreads();
    // stage input tile with halo: 6 rows x 66 cols x 32 ci, zero-padded OOB,
    // chunk index XOR-swizzled by (pc>>1)&3
    for (int idx = t; idx < 1584; idx += 256) {
      int c2 = idx & 3;
      int pc = idx >> 2;             // 0..395
      int row = pc / 66, col = pc - row * 66;
      int gy = y0 + row - 1, gx = col - 1;
      f16x8 v = {};
      if ((unsigned)gy < 64u && (unsigned)gx < 64u)
        v = *(const f16x8*)&xin[(((size_t)b * 64 + gy) * 64 + gx) * C + ck * 32 + c2 * 8];
      *(f16x8*)(xsb + pc * 64 + ((c2 ^ ((pc >> 1) & 3)) << 4)) = v;
    }
    __syncthreads();

#pragma unroll
    for (int tap = 0; tap < 9; ++tap) {
      const int dy = tap / 3, dx = tap % 3;
      f16x8 af[4], bf[4];
#pragma unroll
      for (int m = 0; m < 4; ++m)
        af[m] = *(const f16x8*)&Wp[((size_t)(tap * C + co_base + m * 16 + ln)) * C + ck * 32 + kg * 8];
#pragma unroll
      for (int n = 0; n < 4; ++n) {
        int pc = (wid + dy) * 66 + n * 16 + ln + dx;
        bf[n] = *(const f16x8*)(xsb + pc * 64 + ((kg ^ ((pc >> 1) & 3)) << 4));
      }
#pragma unroll
      for (int m = 0; m < 4; ++m)
#pragma unroll
        for (int n = 0; n < 4; ++n)
          acc[m][n] = __builtin_amdgcn_mfma_f32_16x16x32_f16(af[m], bf[n], acc[m][n], 0, 0, 0);
    }
  }

  int yo = y0 + wid;
  if (out_nhwc) {
#pragma unroll
    for (int m = 0; m < 4; ++m) {
      int cog = co_base + m * 16 + kg * 4;
      f32x4 d4 = *(const f32x4*)&dmod[b * C + cog];
      f32x4 n4 = *(const f32x4*)&nscale[cog];
      f32x4 s4 = *(const f32x4*)&s2v[b * C + cog];
#pragma unroll
      for (int n = 0; n < 4; ++n) {
        int xo = n * 16 + ln;
        float nz = noise[b * HW + yo * 64 + xo];
        f16x4 o;
#pragma unroll
        for (int r = 0; r < 4; ++r) {
          float v = fmaf(acc[m][n][r], d4[r], n4[r] * nz);
          v = v >= 0.f ? v : LRELU * v;
          o[r] = (f16)(v * s4[r]);
        }
        *(f16x4*)&out_nhwc[(((size_t)b * 64 + yo) * 64 + xo) * C + cog] = o;
      }
    }
  } else {
#pragma unroll
    for (int m = 0; m < 4; ++m) {
      int cog = co_base + m * 16 + kg * 4;
      f32x4 d4 = *(const f32x4*)&dmod[b * C + cog];
      f32x4 n4 = *(const f32x4*)&nscale[cog];
#pragma unroll
      for (int n = 0; n < 4; ++n) {
        int xo = n * 16 + ln;
        float nz = noise[b * HW + yo * 64 + xo];
#pragma unroll
        for (int r = 0; r < 4; ++r) {
          float v = fmaf(acc[m][n][r], d4[r], n4[r] * nz);
          v = v >= 0.f ? v : LRELU * v;
          out_nchw[(((size_t)b * C + cog + r) * 64 + yo) * 64 + xo] = v;
        }
      }
    }
  }
}

// ---------------------------------------------------------------------------
// 1x1 toRGB: rgb[b][c][p] = sum_co (rgbW[c][co] * sr[b][co]) * h[b][co][p]
// grid = B*16 blocks, 256 threads (256 px per block)
__global__ void k_rgb(const float* __restrict__ h,    // [B][C][HW] fp32
                      const float* __restrict__ rw,   // [3][C]
                      const float* __restrict__ sr,   // [B][C]
                      float* __restrict__ rgb) {      // [B][3][HW]
  __shared__ float wsr[3][C];
  int bx = blockIdx.x;
  int b = bx >> 4;
  int chunk = bx & 15;
  int t = threadIdx.x;
  for (int idx = t; idx < 3 * C; idx += 256) {
    int c = idx >> 9, co = idx & 511;
    wsr[c][co] = rw[c * C + co] * sr[b * C + co];
  }
  __syncthreads();
  int px = chunk * 256 + t;
  float a0 = 0.f, a1 = 0.f, a2 = 0.f;
  const float* hp = h + (size_t)b * C * HW + px;
#pragma unroll 4
  for (int co = 0; co < C; ++co) {
    float hv = hp[(size_t)co * HW];
    a0 = fmaf(wsr[0][co], hv, a0);
    a1 = fmaf(wsr[1][co], hv, a1);
    a2 = fmaf(wsr[2][co], hv, a2);
  }
  float* rp = rgb + (size_t)b * 3 * HW + px;
  rp[0] = a0;
  rp[HW] = a1;
  rp[2 * HW] = a2;
}

// ---------------------------------------------------------------------------
extern "C" void kernel_launch(void* const* d_in, const int* in_sizes, int n_in,
                              void* d_out, int out_size, void* d_ws, size_t ws_size,
                              hipStream_t stream) {
  (void)in_sizes; (void)n_in; (void)out_size; (void)ws_size;
  const float* x   = (const float*)d_in[0];
  const float* wst = (const float*)d_in[1];
  const float* w1  = (const float*)d_in[2];
  const float* m1w = (const float*)d_in[3];
  const float* m1b = (const float*)d_in[4];
  const float* ns1 = (const float*)d_in[5];
  const float* w2  = (const float*)d_in[6];
  const float* m2w = (const float*)d_in[7];
  const float* m2b = (const float*)d_in[8];
  const float* ns2 = (const float*)d_in[9];
  const float* rw  = (const float*)d_in[10];
  const float* mrw = (const float*)d_in[11];
  const float* mrb = (const float*)d_in[12];
  const float* nz1 = (const float*)d_in[13];
  const float* nz2 = (const float*)d_in[14];

  char* wsb = (char*)d_ws;
  f16*   xup  = (f16*)(wsb + XUP_B);
  f16*   h1s  = (f16*)(wsb + H1S_B);
  f16*   wp1  = (f16*)(wsb + WP1_B);
  f16*   wp2  = (f16*)(wsb + WP2_B);
  float* s1   = (float*)(wsb + S1_B);
  float* s2   = (float*)(wsb + S2_B);
  float* srr  = (float*)(wsb + SR_B);
  float* dm1  = (float*)(wsb + D1_B);
  float* dm2  = (float*)(wsb + D2_B);
  float* wsq1 = (float*)(wsb + WSQ1_B);
  float* wsq2 = (float*)(wsb + WSQ2_B);

  float* hout   = (float*)d_out;                  // [B][C][HW]
  float* rgbout = hout + (size_t)B * C * HW;      // [B][3][HW]

  k_styles3<<<dim3(B, 3), 256, 0, stream>>>(wst, m1w, m1b, s1, m2w, m2b, s2, mrw, mrb, srr);
  k_packw<<<C * C / 256, 256, 0, stream>>>(w1, wp1, wsq1);
  k_packw<<<C * C / 256, 256, 0, stream>>>(w2, wp2, wsq2);
  k_demod<<<C, 256, 0, stream>>>(wsq1, s1, dm1);
  k_demod<<<C, 256, 0, stream>>>(wsq2, s2, dm2);
  k_up<<<B * 64, 256, 0, stream>>>(x, s1, xup);
  k_conv_mfma<<<1024, 256, 0, stream>>>(xup, wp1, dm1, ns1, nz1, s2, h1s, nullptr);
  k_conv_mfma<<<1024, 256, 0, stream>>>(h1s, wp2, dm2, ns2, nz2, nullptr, nullptr, hout);
  k_rgb<<<B * 16, 256, 0, stream>>>(hout, rw, srr, rgbout);
}

// Round 4
// 747.664 us; speedup vs baseline: 1.3857x; 1.3857x over previous
//
#include <hip/hip_runtime.h>

#define LRELU 0.2f
#define EPS_D 1e-8f

static constexpr int B = 8;
static constexpr int C = 512;
static constexpr int HO = 64, WO = 64;
static constexpr int HW = HO * WO;     // 4096
static constexpr int HIN = 32;

typedef _Float16 f16;
typedef _Float16 f16x8 __attribute__((ext_vector_type(8)));
typedef _Float16 f16x4 __attribute__((ext_vector_type(4)));
typedef float f32x4 __attribute__((ext_vector_type(4)));

// workspace byte offsets
static constexpr size_t XUP_B  = 0;                         // [B][64][64][512] f16
static constexpr size_t H1S_B  = 33554432;                  // [B][64][64][512] f16
static constexpr size_t WP1_B  = 67108864;                  // [9][512][512] f16
static constexpr size_t WP2_B  = 71827456;                  // [9][512][512] f16
static constexpr size_t S1_B   = 76546048;                  // [B][C] f32
static constexpr size_t S2_B   = S1_B + 16384;
static constexpr size_t SR_B   = S2_B + 16384;
static constexpr size_t D1_B   = SR_B + 16384;
static constexpr size_t D2_B   = D1_B + 16384;
static constexpr size_t WSQ1_B = D2_B + 16384;              // [C][C] f32
static constexpr size_t WSQ2_B = WSQ1_B + 1048576;

// ---------------------------------------------------------------------------
// styles x3 fused: s[b][i] = mod_b[i] + sum_j w[b][j] * mod_w[i][j]
__global__ void k_styles3(const float* __restrict__ wsty,
                          const float* __restrict__ mw0, const float* __restrict__ mb0, float* __restrict__ so0,
                          const float* __restrict__ mw1, const float* __restrict__ mb1, float* __restrict__ so1,
                          const float* __restrict__ mw2, const float* __restrict__ mb2, float* __restrict__ so2) {
  __shared__ float wsh[C];
  int b = blockIdx.x;
  int which = blockIdx.y;
  const float* mw = which == 0 ? mw0 : (which == 1 ? mw1 : mw2);
  const float* mb = which == 0 ? mb0 : (which == 1 ? mb1 : mb2);
  float* sout     = which == 0 ? so0 : (which == 1 ? so1 : so2);
  int t = threadIdx.x;
  wsh[t]       = wsty[b * C + t];
  wsh[t + 256] = wsty[b * C + t + 256];
  __syncthreads();
  for (int i = t; i < C; i += 256) {
    float acc = mb[i];
    const float* row = mw + (size_t)i * C;
#pragma unroll 4
    for (int j = 0; j < C; ++j) acc = fmaf(wsh[j], row[j], acc);
    sout[b * C + i] = acc;
  }
}

// ---------------------------------------------------------------------------
// weight prepack: W fp32 [co][ci][9] -> Wp f16 [tap][co][ci], plus
// wsq[co*C+ci] = sum_tap W^2 (for demod)
__global__ void k_packw(const float* __restrict__ w, f16* __restrict__ wp,
                        float* __restrict__ wsq) {
  int idx = blockIdx.x * 256 + threadIdx.x;   // co*512+ci
  const float* src = w + (size_t)idx * 9;
  float acc = 0.f;
#pragma unroll
  for (int tap = 0; tap < 9; ++tap) {
    float v = src[tap];
    wp[(size_t)tap * (C * C) + idx] = (f16)v;
    acc = fmaf(v, v, acc);
  }
  wsq[idx] = acc;
}

// ---------------------------------------------------------------------------
// demod: d[b][co] = rsqrt( sum_ci s[b][ci]^2 * wsq[co][ci] + eps )
__global__ void k_demod(const float* __restrict__ wsq,  // [C][C]
                        const float* __restrict__ s,    // [B][C]
                        float* __restrict__ dout) {     // [B][C]
  __shared__ float ssq[B * C];
  __shared__ float red[4][B];
  int co = blockIdx.x;
  int t = threadIdx.x;
  for (int idx = t; idx < B * C; idx += 256) {
    float v = s[idx];
    ssq[idx] = v * v;
  }
  __syncthreads();
  int ci0 = t * 2;
  float w0 = wsq[(size_t)co * C + ci0];
  float w1 = wsq[(size_t)co * C + ci0 + 1];
  float p[B];
#pragma unroll
  for (int b = 0; b < B; ++b) {
    p[b] = fmaf(ssq[b * C + ci0], w0, ssq[b * C + ci0 + 1] * w1);
  }
  int lane = t & 63, wv = t >> 6;
#pragma unroll
  for (int b = 0; b < B; ++b) {
    float v = p[b];
    for (int off = 32; off; off >>= 1) v += __shfl_down(v, off);
    if (lane == 0) red[wv][b] = v;
  }
  __syncthreads();
  if (t < B) {
    float tot = red[0][t] + red[1][t] + red[2][t] + red[3][t];
    dout[t * C + co] = rsqrtf(tot + EPS_D);
  }
}

// ---------------------------------------------------------------------------
__device__ __forceinline__ void up1d(int o, int& i0, int& i1, float& w0, float& w1) {
  float src = 0.5f * (float)o - 0.25f;
  float f = floorf(src);
  float fr = src - f;
  int i = (int)f;
  i0 = i < 0 ? 0 : i;
  int j = i + 1;
  i1 = j > (HIN - 1) ? (HIN - 1) : j;
  w1 = fr;
  w0 = 1.0f - fr;
}

// bilinear 2x upsample + s1 scale, NCHW fp32 -> NHWC f16.
// grid = B * 16 (ci chunks of 32) * 4 (yo quarters), 256 threads, 20KB LDS
__global__ __launch_bounds__(256) void k_up(const float* __restrict__ x,
                                            const float* __restrict__ s1,
                                            f16* __restrict__ xup) {
  __shared__ f16 xt[10 * 32 * 32];  // [(yl*32+x)*32 + ci]
  int bx = blockIdx.x;
  int b = bx >> 6;
  int ci0 = ((bx >> 2) & 15) * 32;
  int q = bx & 3;
  int ybase = q * 8 - 1;            // src rows ybase..ybase+9 (clamped)
  int t = threadIdx.x;
  int xi_ = t & 31, cl = t >> 5;    // cl 0..7
  for (int yl = 0; yl < 10; ++yl) {
    int y = ybase + yl;
    y = y < 0 ? 0 : (y > 31 ? 31 : y);
#pragma unroll
    for (int p = 0; p < 4; ++p) {
      int ci = p * 8 + cl;
      xt[(yl * 32 + xi_) * 32 + ci] =
          (f16)x[(((size_t)b * C + ci0 + ci) * 32 + y) * 32 + xi_];
    }
  }
  __syncthreads();
  int xo = t >> 2;          // 0..63
  int cg = (t & 3) * 8;
  float sv[8];
#pragma unroll
  for (int e = 0; e < 8; ++e) sv[e] = s1[b * C + ci0 + cg + e];
  int x0, x1; float wx0, wx1;
  up1d(xo, x0, x1, wx0, wx1);
  for (int yy = 0; yy < 16; ++yy) {
    int yo = q * 16 + yy;
    int y0, y1; float wy0, wy1;
    up1d(yo, y0, y1, wy0, wy1);
    int yl0 = y0 - ybase, yl1 = y1 - ybase;
    f16x8 t00 = *(const f16x8*)&xt[(yl0 * 32 + x0) * 32 + cg];
    f16x8 t01 = *(const f16x8*)&xt[(yl0 * 32 + x1) * 32 + cg];
    f16x8 t10 = *(const f16x8*)&xt[(yl1 * 32 + x0) * 32 + cg];
    f16x8 t11 = *(const f16x8*)&xt[(yl1 * 32 + x1) * 32 + cg];
    f16x8 o;
#pragma unroll
    for (int e = 0; e < 8; ++e) {
      float v = wy0 * (wx0 * (float)t00[e] + wx1 * (float)t01[e]) +
                wy1 * (wx0 * (float)t10[e] + wx1 * (float)t11[e]);
      o[e] = (f16)(v * sv[e]);
    }
    *(f16x8*)&xup[(((size_t)b * 64 + yo) * 64 + xo) * C + ci0 + cg] = o;
  }
}

// ---------------------------------------------------------------------------
// MFMA implicit-GEMM 3x3 conv. Input NHWC f16 (style pre-applied), weights
// [tap][co][ci] f16. Both operands LDS-staged (weights reused by all 4 waves),
// BOTH tiles XOR-swizzled (chunk ^= (row>>1)&3) to kill the stride-64B
// 8-way bank conflicts on fragment ds_read_b128s.
// Block: 64 co x 256 px (4 rows x 64 cols), 4 waves, wave = 64co x 64px.
__global__ __launch_bounds__(256) void k_conv_mfma(
    const f16* __restrict__ xin,      // [B][64][64][C]
    const f16* __restrict__ Wp,       // [9][C][C]
    const float* __restrict__ dmod,   // [B][C]
    const float* __restrict__ nscale, // [C]
    const float* __restrict__ noise,  // [B][HW]
    const float* __restrict__ s2v,    // [B][C] (conv1 only)
    f16* __restrict__ out_nhwc,       // conv1 out or null
    float* __restrict__ out_nchw) {   // conv2 out or null
  __shared__ char xsb[6 * 66 * 64];   // swizzled: [pc][4 chunks of 16B] 25344B
  __shared__ char wsb[9 * 64 * 64];   // swizzled: [tap*64+co][4 chunks]  36864B

  int bx = blockIdx.x;
  int b = bx >> 7;
  int rem = bx & 127;
  int co_base = (rem >> 4) * 64;
  int y0 = (rem & 15) * 4;
  int t = threadIdx.x;
  int lane = t & 63, wid = t >> 6;
  int ln = lane & 15, kg = lane >> 4;

  f32x4 acc[4][4] = {};

  for (int ck = 0; ck < 16; ++ck) {
    __syncthreads();
    // stage input tile with halo: 6 rows x 66 cols x 32 ci, zero-padded OOB
    for (int idx = t; idx < 1584; idx += 256) {
      int c2 = idx & 3;
      int pc = idx >> 2;             // 0..395
      int row = pc / 66, col = pc - row * 66;
      int gy = y0 + row - 1, gx = col - 1;
      f16x8 v = {};
      if ((unsigned)gy < 64u && (unsigned)gx < 64u)
        v = *(const f16x8*)&xin[(((size_t)b * 64 + gy) * 64 + gx) * C + ck * 32 + c2 * 8];
      *(f16x8*)(xsb + pc * 64 + ((c2 ^ ((pc >> 1) & 3)) << 4)) = v;
    }
    // stage weights: 9 taps x 64 co x 32 ci, same swizzle on co row index
    {
      const f16* wsrc = Wp + (size_t)co_base * C + (size_t)ck * 32;
#pragma unroll
      for (int i = 0; i < 9; ++i) {
        int idx = i * 256 + t;
        int c2 = idx & 3;
        int co = (idx >> 2) & 63;
        int tap = idx >> 8;
        f16x8 v = *(const f16x8*)&wsrc[((size_t)tap * C + co) * C + c2 * 8];
        *(f16x8*)(wsb + (tap * 64 + co) * 64 + ((c2 ^ ((co >> 1) & 3)) << 4)) = v;
      }
    }
    __syncthreads();

#pragma unroll
    for (int tap = 0; tap < 9; ++tap) {
      const int dy = tap / 3, dx = tap % 3;
      f16x8 af[4], bf[4];
#pragma unroll
      for (int m = 0; m < 4; ++m) {
        int co_l = m * 16 + ln;
        af[m] = *(const f16x8*)(wsb + (tap * 64 + co_l) * 64 + ((kg ^ ((co_l >> 1) & 3)) << 4));
      }
#pragma unroll
      for (int n = 0; n < 4; ++n) {
        int pc = (wid + dy) * 66 + n * 16 + ln + dx;
        bf[n] = *(const f16x8*)(xsb + pc * 64 + ((kg ^ ((pc >> 1) & 3)) << 4));
      }
#pragma unroll
      for (int m = 0; m < 4; ++m)
#pragma unroll
        for (int n = 0; n < 4; ++n)
          acc[m][n] = __builtin_amdgcn_mfma_f32_16x16x32_f16(af[m], bf[n], acc[m][n], 0, 0, 0);
    }
  }

  int yo = y0 + wid;
  if (out_nhwc) {
#pragma unroll
    for (int m = 0; m < 4; ++m) {
      int cog = co_base + m * 16 + kg * 4;
      f32x4 d4 = *(const f32x4*)&dmod[b * C + cog];
      f32x4 n4 = *(const f32x4*)&nscale[cog];
      f32x4 s4 = *(const f32x4*)&s2v[b * C + cog];
#pragma unroll
      for (int n = 0; n < 4; ++n) {
        int xo = n * 16 + ln;
        float nz = noise[b * HW + yo * 64 + xo];
        f16x4 o;
#pragma unroll
        for (int r = 0; r < 4; ++r) {
          float v = fmaf(acc[m][n][r], d4[r], n4[r] * nz);
          v = v >= 0.f ? v : LRELU * v;
          o[r] = (f16)(v * s4[r]);
        }
        *(f16x4*)&out_nhwc[(((size_t)b * 64 + yo) * 64 + xo) * C + cog] = o;
      }
    }
  } else {
#pragma unroll
    for (int m = 0; m < 4; ++m) {
      int cog = co_base + m * 16 + kg * 4;
      f32x4 d4 = *(const f32x4*)&dmod[b * C + cog];
      f32x4 n4 = *(const f32x4*)&nscale[cog];
#pragma unroll
      for (int n = 0; n < 4; ++n) {
        int xo = n * 16 + ln;
        float nz = noise[b * HW + yo * 64 + xo];
#pragma unroll
        for (int r = 0; r < 4; ++r) {
          float v = fmaf(acc[m][n][r], d4[r], n4[r] * nz);
          v = v >= 0.f ? v : LRELU * v;
          out_nchw[(((size_t)b * C + cog + r) * 64 + yo) * 64 + xo] = v;
        }
      }
    }
  }
}

// ---------------------------------------------------------------------------
// 1x1 toRGB: rgb[b][c][p] = sum_co (rgbW[c][co] * sr[b][co]) * h[b][co][p]
__global__ void k_rgb(const float* __restrict__ h,    // [B][C][HW] fp32
                      const float* __restrict__ rw,   // [3][C]
                      const float* __restrict__ sr,   // [B][C]
                      float* __restrict__ rgb) {      // [B][3][HW]
  __shared__ float wsr[3][C];
  int bx = blockIdx.x;
  int b = bx >> 4;
  int chunk = bx & 15;
  int t = threadIdx.x;
  for (int idx = t; idx < 3 * C; idx += 256) {
    int c = idx >> 9, co = idx & 511;
    wsr[c][co] = rw[c * C + co] * sr[b * C + co];
  }
  __syncthreads();
  int px = chunk * 256 + t;
  float a0 = 0.f, a1 = 0.f, a2 = 0.f;
  const float* hp = h + (size_t)b * C * HW + px;
#pragma unroll 4
  for (int co = 0; co < C; ++co) {
    float hv = hp[(size_t)co * HW];
    a0 = fmaf(wsr[0][co], hv, a0);
    a1 = fmaf(wsr[1][co], hv, a1);
    a2 = fmaf(wsr[2][co], hv, a2);
  }
  float* rp = rgb + (size_t)b * 3 * HW + px;
  rp[0] = a0;
  rp[HW] = a1;
  rp[2 * HW] = a2;
}

// ---------------------------------------------------------------------------
extern "C" void kernel_launch(void* const* d_in, const int* in_sizes, int n_in,
                              void* d_out, int out_size, void* d_ws, size_t ws_size,
                              hipStream_t stream) {
  (void)in_sizes; (void)n_in; (void)out_size; (void)ws_size;
  const float* x   = (const float*)d_in[0];
  const float* wst = (const float*)d_in[1];
  const float* w1  = (const float*)d_in[2];
  const float* m1w = (const float*)d_in[3];
  const float* m1b = (const float*)d_in[4];
  const float* ns1 = (const float*)d_in[5];
  const float* w2  = (const float*)d_in[6];
  const float* m2w = (const float*)d_in[7];
  const float* m2b = (const float*)d_in[8];
  const float* ns2 = (const float*)d_in[9];
  const float* rw  = (const float*)d_in[10];
  const float* mrw = (const float*)d_in[11];
  const float* mrb = (const float*)d_in[12];
  const float* nz1 = (const float*)d_in[13];
  const float* nz2 = (const float*)d_in[14];

  char* wsb = (char*)d_ws;
  f16*   xup  = (f16*)(wsb + XUP_B);
  f16*   h1s  = (f16*)(wsb + H1S_B);
  f16*   wp1  = (f16*)(wsb + WP1_B);
  f16*   wp2  = (f16*)(wsb + WP2_B);
  float* s1   = (float*)(wsb + S1_B);
  float* s2   = (float*)(wsb + S2_B);
  float* srr  = (float*)(wsb + SR_B);
  float* dm1  = (float*)(wsb + D1_B);
  float* dm2  = (float*)(wsb + D2_B);
  float* wsq1 = (float*)(wsb + WSQ1_B);
  float* wsq2 = (float*)(wsb + WSQ2_B);

  float* hout   = (float*)d_out;                  // [B][C][HW]
  float* rgbout = hout + (size_t)B * C * HW;      // [B][3][HW]

  k_styles3<<<dim3(B, 3), 256, 0, stream>>>(wst, m1w, m1b, s1, m2w, m2b, s2, mrw, mrb, srr);
  k_packw<<<C * C / 256, 256, 0, stream>>>(w1, wp1, wsq1);
  k_packw<<<C * C / 256, 256, 0, stream>>>(w2, wp2, wsq2);
  k_demod<<<C, 256, 0, stream>>>(wsq1, s1, dm1);
  k_demod<<<C, 256, 0, stream>>>(wsq2, s2, dm2);
  k_up<<<B * 64, 256, 0, stream>>>(x, s1, xup);
  k_conv_mfma<<<1024, 256, 0, stream>>>(xup, wp1, dm1, ns1, nz1, s2, h1s, nullptr);
  k_conv_mfma<<<1024, 256, 0, stream>>>(h1s, wp2, dm2, ns2, nz2, nullptr, nullptr, hout);
  k_rgb<<<B * 16, 256, 0, stream>>>(hout, rw, srr, rgbout);
}

// Round 5
// 506.812 us; speedup vs baseline: 2.0442x; 1.4752x over previous
//
#include <hip/hip_runtime.h>

#define LRELU 0.2f
#define EPS_D 1e-8f

static constexpr int B = 8;
static constexpr int C = 512;
static constexpr int HO = 64, WO = 64;
static constexpr int HW = HO * WO;     // 4096
static constexpr int HIN = 32;

typedef _Float16 f16;
typedef _Float16 f16x8 __attribute__((ext_vector_type(8)));
typedef _Float16 f16x4 __attribute__((ext_vector_type(4)));
typedef float f32x4 __attribute__((ext_vector_type(4)));

// workspace byte offsets
static constexpr size_t XUP_B  = 0;                         // [B][64][64][512] f16
static constexpr size_t H1S_B  = 33554432;                  // [B][64][64][512] f16
static constexpr size_t WP1_B  = 67108864;                  // [9][512][512] f16
static constexpr size_t WP2_B  = 71827456;                  // [9][512][512] f16
static constexpr size_t S1_B   = 76546048;                  // [B][C] f32
static constexpr size_t S2_B   = S1_B + 16384;
static constexpr size_t SR_B   = S2_B + 16384;
static constexpr size_t D1_B   = SR_B + 16384;
static constexpr size_t D2_B   = D1_B + 16384;
static constexpr size_t WSQ1_B = D2_B + 16384;              // [C][C] f32
static constexpr size_t WSQ2_B = WSQ1_B + 1048576;

// ---------------------------------------------------------------------------
// styles x3 fused
__global__ void k_styles3(const float* __restrict__ wsty,
                          const float* __restrict__ mw0, const float* __restrict__ mb0, float* __restrict__ so0,
                          const float* __restrict__ mw1, const float* __restrict__ mb1, float* __restrict__ so1,
                          const float* __restrict__ mw2, const float* __restrict__ mb2, float* __restrict__ so2) {
  __shared__ float wsh[C];
  int b = blockIdx.x;
  int which = blockIdx.y;
  const float* mw = which == 0 ? mw0 : (which == 1 ? mw1 : mw2);
  const float* mb = which == 0 ? mb0 : (which == 1 ? mb1 : mb2);
  float* sout     = which == 0 ? so0 : (which == 1 ? so1 : so2);
  int t = threadIdx.x;
  wsh[t]       = wsty[b * C + t];
  wsh[t + 256] = wsty[b * C + t + 256];
  __syncthreads();
  for (int i = t; i < C; i += 256) {
    float acc = mb[i];
    const float* row = mw + (size_t)i * C;
#pragma unroll 4
    for (int j = 0; j < C; ++j) acc = fmaf(wsh[j], row[j], acc);
    sout[b * C + i] = acc;
  }
}

// ---------------------------------------------------------------------------
// weight prepack: W fp32 [co][ci][9] -> Wp f16 [tap][co][ci], plus wsq
__global__ void k_packw(const float* __restrict__ w, f16* __restrict__ wp,
                        float* __restrict__ wsq) {
  int idx = blockIdx.x * 256 + threadIdx.x;   // co*512+ci
  const float* src = w + (size_t)idx * 9;
  float acc = 0.f;
#pragma unroll
  for (int tap = 0; tap < 9; ++tap) {
    float v = src[tap];
    wp[(size_t)tap * (C * C) + idx] = (f16)v;
    acc = fmaf(v, v, acc);
  }
  wsq[idx] = acc;
}

// ---------------------------------------------------------------------------
// demod: d[b][co] = rsqrt( sum_ci s[b][ci]^2 * wsq[co][ci] + eps )
__global__ void k_demod(const float* __restrict__ wsq,  // [C][C]
                        const float* __restrict__ s,    // [B][C]
                        float* __restrict__ dout) {     // [B][C]
  __shared__ float ssq[B * C];
  __shared__ float red[4][B];
  int co = blockIdx.x;
  int t = threadIdx.x;
  for (int idx = t; idx < B * C; idx += 256) {
    float v = s[idx];
    ssq[idx] = v * v;
  }
  __syncthreads();
  int ci0 = t * 2;
  float w0 = wsq[(size_t)co * C + ci0];
  float w1 = wsq[(size_t)co * C + ci0 + 1];
  float p[B];
#pragma unroll
  for (int b = 0; b < B; ++b) {
    p[b] = fmaf(ssq[b * C + ci0], w0, ssq[b * C + ci0 + 1] * w1);
  }
  int lane = t & 63, wv = t >> 6;
#pragma unroll
  for (int b = 0; b < B; ++b) {
    float v = p[b];
    for (int off = 32; off; off >>= 1) v += __shfl_down(v, off);
    if (lane == 0) red[wv][b] = v;
  }
  __syncthreads();
  if (t < B) {
    float tot = red[0][t] + red[1][t] + red[2][t] + red[3][t];
    dout[t * C + co] = rsqrtf(tot + EPS_D);
  }
}

// ---------------------------------------------------------------------------
__device__ __forceinline__ void up1d(int o, int& i0, int& i1, float& w0, float& w1) {
  float src = 0.5f * (float)o - 0.25f;
  float f = floorf(src);
  float fr = src - f;
  int i = (int)f;
  i0 = i < 0 ? 0 : i;
  int j = i + 1;
  i1 = j > (HIN - 1) ? (HIN - 1) : j;
  w1 = fr;
  w0 = 1.0f - fr;
}

// bilinear 2x upsample + s1 scale, NCHW fp32 -> NHWC f16.
__global__ __launch_bounds__(256) void k_up(const float* __restrict__ x,
                                            const float* __restrict__ s1,
                                            f16* __restrict__ xup) {
  __shared__ f16 xt[10 * 32 * 32];  // [(yl*32+x)*32 + ci]
  int bx = blockIdx.x;
  int b = bx >> 6;
  int ci0 = ((bx >> 2) & 15) * 32;
  int q = bx & 3;
  int ybase = q * 8 - 1;            // src rows ybase..ybase+9 (clamped)
  int t = threadIdx.x;
  int xi_ = t & 31, cl = t >> 5;    // cl 0..7
  for (int yl = 0; yl < 10; ++yl) {
    int y = ybase + yl;
    y = y < 0 ? 0 : (y > 31 ? 31 : y);
#pragma unroll
    for (int p = 0; p < 4; ++p) {
      int ci = p * 8 + cl;
      xt[(yl * 32 + xi_) * 32 + ci] =
          (f16)x[(((size_t)b * C + ci0 + ci) * 32 + y) * 32 + xi_];
    }
  }
  __syncthreads();
  int xo = t >> 2;          // 0..63
  int cg = (t & 3) * 8;
  float sv[8];
#pragma unroll
  for (int e = 0; e < 8; ++e) sv[e] = s1[b * C + ci0 + cg + e];
  int x0, x1; float wx0, wx1;
  up1d(xo, x0, x1, wx0, wx1);
  for (int yy = 0; yy < 16; ++yy) {
    int yo = q * 16 + yy;
    int y0, y1; float wy0, wy1;
    up1d(yo, y0, y1, wy0, wy1);
    int yl0 = y0 - ybase, yl1 = y1 - ybase;
    f16x8 t00 = *(const f16x8*)&xt[(yl0 * 32 + x0) * 32 + cg];
    f16x8 t01 = *(const f16x8*)&xt[(yl0 * 32 + x1) * 32 + cg];
    f16x8 t10 = *(const f16x8*)&xt[(yl1 * 32 + x0) * 32 + cg];
    f16x8 t11 = *(const f16x8*)&xt[(yl1 * 32 + x1) * 32 + cg];
    f16x8 o;
#pragma unroll
    for (int e = 0; e < 8; ++e) {
      float v = wy0 * (wx0 * (float)t00[e] + wx1 * (float)t01[e]) +
                wy1 * (wx0 * (float)t10[e] + wx1 * (float)t11[e]);
      o[e] = (f16)(v * sv[e]);
    }
    *(f16x8*)&xup[(((size_t)b * 64 + yo) * 64 + xo) * C + ci0 + cg] = o;
  }
}

// ---------------------------------------------------------------------------
// MFMA implicit-GEMM 3x3 conv, LDS-read-intensity-optimized.
// Block: 128 co x 256 px (4 rows x 64 cols), 4 waves; wave = 128co x 64px
// (one row), acc 8x4 f32x4. K-chunk = 32 ci; weights staged 3 taps (one dy)
// at a time. K-major padded LDS layouts (affine, conflict-free):
//   xs:   [c2(4)][pc(396)][16B]  region stride 6336B (16-bank shift)
//   wsm3: [dx*4+c2(12)][co(128)][16B] region stride 2112B (16-bank shift)
// grid = 512 blocks = exactly 2/CU.
__global__ __launch_bounds__(256, 2) void k_conv_mfma(
    const f16* __restrict__ xin,      // [B][64][64][C]
    const f16* __restrict__ Wp,       // [9][C][C]
    const float* __restrict__ dmod,   // [B][C]
    const float* __restrict__ nscale, // [C]
    const float* __restrict__ noise,  // [B][HW]
    const float* __restrict__ s2v,    // [B][C] (conv1 only)
    f16* __restrict__ out_nhwc,       // conv1 out or null
    float* __restrict__ out_nchw) {   // conv2 out or null
  __shared__ char xsb[4 * 6336];      // 25344B
  __shared__ char wsb3[12 * 2112];    // 25344B

  int bx = blockIdx.x;
  int b = bx >> 6;
  int rem = bx & 63;
  int co_base = (rem >> 4) * 128;
  int y0 = (rem & 15) * 4;
  int t = threadIdx.x;
  int lane = t & 63, wid = t >> 6;
  int ln = lane & 15, kg = lane >> 4;

  f32x4 acc[8][4] = {};

  for (int ck = 0; ck < 16; ++ck) {
    for (int dyg = 0; dyg < 3; ++dyg) {
      __syncthreads();
      if (dyg == 0) {
        // stage input tile with halo: 6 rows x 66 cols x 32 ci (1584 chunks)
        for (int idx = t; idx < 1584; idx += 256) {
          int c2 = idx & 3;
          int pc = idx >> 2;             // 0..395
          int row = pc / 66, col = pc - row * 66;
          int gy = y0 + row - 1, gx = col - 1;
          f16x8 v = {};
          if ((unsigned)gy < 64u && (unsigned)gx < 64u)
            v = *(const f16x8*)&xin[(((size_t)b * 64 + gy) * 64 + gx) * C + ck * 32 + c2 * 8];
          *(f16x8*)(xsb + c2 * 6336 + pc * 16) = v;
        }
      }
      // stage weights for 3 taps (dy = dyg, dx = 0..2): 1536 chunks, 6 iters
#pragma unroll
      for (int i = 0; i < 6; ++i) {
        int idx = i * 256 + t;
        int c2 = idx & 3;
        int co = (idx >> 2) & 127;
        int dx = idx >> 9;             // 0..2
        f16x8 v = *(const f16x8*)&Wp[((size_t)((dyg * 3 + dx) * C) + co_base + co) * C + ck * 32 + c2 * 8];
        *(f16x8*)(wsb3 + (dx * 4 + c2) * 2112 + co * 16) = v;
      }
      __syncthreads();

#pragma unroll
      for (int dx = 0; dx < 3; ++dx) {
        f16x8 af[8], bf[4];
#pragma unroll
        for (int m = 0; m < 8; ++m)
          af[m] = *(const f16x8*)(wsb3 + (dx * 4 + kg) * 2112 + (m * 16 + ln) * 16);
        int pcb = (wid + dyg) * 66 + ln + dx;
#pragma unroll
        for (int n = 0; n < 4; ++n)
          bf[n] = *(const f16x8*)(xsb + kg * 6336 + (pcb + n * 16) * 16);
#pragma unroll
        for (int m = 0; m < 8; ++m)
#pragma unroll
          for (int n = 0; n < 4; ++n)
            acc[m][n] = __builtin_amdgcn_mfma_f32_16x16x32_f16(af[m], bf[n], acc[m][n], 0, 0, 0);
      }
    }
  }

  // epilogue
  int yo = y0 + wid;
  float nz[4];
#pragma unroll
  for (int n = 0; n < 4; ++n) nz[n] = noise[b * HW + yo * 64 + n * 16 + ln];

  if (out_nhwc) {
#pragma unroll
    for (int m = 0; m < 8; ++m) {
      int cog = co_base + m * 16 + kg * 4;
      f32x4 d4 = *(const f32x4*)&dmod[b * C + cog];
      f32x4 n4 = *(const f32x4*)&nscale[cog];
      f32x4 s4 = *(const f32x4*)&s2v[b * C + cog];
#pragma unroll
      for (int n = 0; n < 4; ++n) {
        int xo = n * 16 + ln;
        f16x4 o;
#pragma unroll
        for (int r = 0; r < 4; ++r) {
          float v = fmaf(acc[m][n][r], d4[r], n4[r] * nz[n]);
          v = v >= 0.f ? v : LRELU * v;
          o[r] = (f16)(v * s4[r]);
        }
        *(f16x4*)&out_nhwc[(((size_t)b * 64 + yo) * 64 + xo) * C + cog] = o;
      }
    }
  } else {
#pragma unroll
    for (int m = 0; m < 8; ++m) {
      int cog = co_base + m * 16 + kg * 4;
      f32x4 d4 = *(const f32x4*)&dmod[b * C + cog];
      f32x4 n4 = *(const f32x4*)&nscale[cog];
#pragma unroll
      for (int n = 0; n < 4; ++n) {
        int xo = n * 16 + ln;
#pragma unroll
        for (int r = 0; r < 4; ++r) {
          float v = fmaf(acc[m][n][r], d4[r], n4[r] * nz[n]);
          v = v >= 0.f ? v : LRELU * v;
          out_nchw[(((size_t)b * C + cog + r) * 64 + yo) * 64 + xo] = v;
        }
      }
    }
  }
}

// ---------------------------------------------------------------------------
// 1x1 toRGB
__global__ void k_rgb(const float* __restrict__ h,    // [B][C][HW] fp32
                      const float* __restrict__ rw,   // [3][C]
                      const float* __restrict__ sr,   // [B][C]
                      float* __restrict__ rgb) {      // [B][3][HW]
  __shared__ float wsr[3][C];
  int bx = blockIdx.x;
  int b = bx >> 4;
  int chunk = bx & 15;
  int t = threadIdx.x;
  for (int idx = t; idx < 3 * C; idx += 256) {
    int c = idx >> 9, co = idx & 511;
    wsr[c][co] = rw[c * C + co] * sr[b * C + co];
  }
  __syncthreads();
  int px = chunk * 256 + t;
  float a0 = 0.f, a1 = 0.f, a2 = 0.f;
  const float* hp = h + (size_t)b * C * HW + px;
#pragma unroll 4
  for (int co = 0; co < C; ++co) {
    float hv = hp[(size_t)co * HW];
    a0 = fmaf(wsr[0][co], hv, a0);
    a1 = fmaf(wsr[1][co], hv, a1);
    a2 = fmaf(wsr[2][co], hv, a2);
  }
  float* rp = rgb + (size_t)b * 3 * HW + px;
  rp[0] = a0;
  rp[HW] = a1;
  rp[2 * HW] = a2;
}

// ---------------------------------------------------------------------------
extern "C" void kernel_launch(void* const* d_in, const int* in_sizes, int n_in,
                              void* d_out, int out_size, void* d_ws, size_t ws_size,
                              hipStream_t stream) {
  (void)in_sizes; (void)n_in; (void)out_size; (void)ws_size;
  const float* x   = (const float*)d_in[0];
  const float* wst = (const float*)d_in[1];
  const float* w1  = (const float*)d_in[2];
  const float* m1w = (const float*)d_in[3];
  const float* m1b = (const float*)d_in[4];
  const float* ns1 = (const float*)d_in[5];
  const float* w2  = (const float*)d_in[6];
  const float* m2w = (const float*)d_in[7];
  const float* m2b = (const float*)d_in[8];
  const float* ns2 = (const float*)d_in[9];
  const float* rw  = (const float*)d_in[10];
  const float* mrw = (const float*)d_in[11];
  const float* mrb = (const float*)d_in[12];
  const float* nz1 = (const float*)d_in[13];
  const float* nz2 = (const float*)d_in[14];

  char* wsb = (char*)d_ws;
  f16*   xup  = (f16*)(wsb + XUP_B);
  f16*   h1s  = (f16*)(wsb + H1S_B);
  f16*   wp1  = (f16*)(wsb + WP1_B);
  f16*   wp2  = (f16*)(wsb + WP2_B);
  float* s1   = (float*)(wsb + S1_B);
  float* s2   = (float*)(wsb + S2_B);
  float* srr  = (float*)(wsb + SR_B);
  float* dm1  = (float*)(wsb + D1_B);
  float* dm2  = (float*)(wsb + D2_B);
  float* wsq1 = (float*)(wsb + WSQ1_B);
  float* wsq2 = (float*)(wsb + WSQ2_B);

  float* hout   = (float*)d_out;                  // [B][C][HW]
  float* rgbout = hout + (size_t)B * C * HW;      // [B][3][HW]

  k_styles3<<<dim3(B, 3), 256, 0, stream>>>(wst, m1w, m1b, s1, m2w, m2b, s2, mrw, mrb, srr);
  k_packw<<<C * C / 256, 256, 0, stream>>>(w1, wp1, wsq1);
  k_packw<<<C * C / 256, 256, 0, stream>>>(w2, wp2, wsq2);
  k_demod<<<C, 256, 0, stream>>>(wsq1, s1, dm1);
  k_demod<<<C, 256, 0, stream>>>(wsq2, s2, dm2);
  k_up<<<B * 64, 256, 0, stream>>>(x, s1, xup);
  k_conv_mfma<<<512, 256, 0, stream>>>(xup, wp1, dm1, ns1, nz1, s2, h1s, nullptr);
  k_conv_mfma<<<512, 256, 0, stream>>>(h1s, wp2, dm2, ns2, nz2, nullptr, nullptr, hout);
  k_rgb<<<B * 16, 256, 0, stream>>>(hout, rw, srr, rgbout);
}

// Round 6
// 469.956 us; speedup vs baseline: 2.2045x; 1.0784x over previous
//
#include <hip/hip_runtime.h>

#define LRELU 0.2f
#define EPS_D 1e-8f

static constexpr int B = 8;
static constexpr int C = 512;
static constexpr int HO = 64, WO = 64;
static constexpr int HW = HO * WO;     // 4096
static constexpr int HIN = 32;

typedef _Float16 f16;
typedef _Float16 f16x8 __attribute__((ext_vector_type(8)));
typedef _Float16 f16x4 __attribute__((ext_vector_type(4)));
typedef float f32x4 __attribute__((ext_vector_type(4)));

// LDS region strides (bytes). 6368B = 1592 dw = 24 (mod 32); 2144B = 536 dw
// = 24 (mod 32) -> kg in {0,1,2,3} shifts bank-quads {0,24,16,8}: distinct.
static constexpr int XSS = 6368;
static constexpr int WSS = 2144;

// workspace byte offsets
static constexpr size_t XUP_B  = 0;                         // [B][64][64][512] f16
static constexpr size_t H1S_B  = 33554432;                  // [B][64][64][512] f16
static constexpr size_t WP1_B  = 67108864;                  // [9][512][512] f16
static constexpr size_t WP2_B  = 71827456;                  // [9][512][512] f16
static constexpr size_t S1_B   = 76546048;                  // [B][C] f32
static constexpr size_t S2_B   = S1_B + 16384;
static constexpr size_t SR_B   = S2_B + 16384;
static constexpr size_t D1_B   = SR_B + 16384;
static constexpr size_t D2_B   = D1_B + 16384;
static constexpr size_t WSQ1_B = D2_B + 16384;              // [C][C] f32
static constexpr size_t WSQ2_B = WSQ1_B + 1048576;

// ---------------------------------------------------------------------------
// styles x3 fused, j-split: grid (B, 3, 4), 256 threads
__global__ void k_styles3(const float* __restrict__ wsty,
                          const float* __restrict__ mw0, const float* __restrict__ mb0, float* __restrict__ so0,
                          const float* __restrict__ mw1, const float* __restrict__ mb1, float* __restrict__ so1,
                          const float* __restrict__ mw2, const float* __restrict__ mb2, float* __restrict__ so2) {
  __shared__ float wsh[C];
  __shared__ float red[128];
  int b = blockIdx.x;
  int which = blockIdx.y;
  int slice = blockIdx.z;
  const float* mw = which == 0 ? mw0 : (which == 1 ? mw1 : mw2);
  const float* mb = which == 0 ? mb0 : (which == 1 ? mb1 : mb2);
  float* sout     = which == 0 ? so0 : (which == 1 ? so1 : so2);
  int t = threadIdx.x;
  wsh[t]       = wsty[b * C + t];
  wsh[t + 256] = wsty[b * C + t + 256];
  __syncthreads();
  int i = slice * 128 + (t & 127);
  int jh = t >> 7;
  const float* row = mw + (size_t)i * C + jh * 256;
  const float* wp = wsh + jh * 256;
  float acc = 0.f;
#pragma unroll 4
  for (int j = 0; j < 256; ++j) acc = fmaf(wp[j], row[j], acc);
  if (t >= 128) red[t - 128] = acc;
  __syncthreads();
  if (t < 128) sout[b * C + i] = acc + red[t] + mb[i];
}

// ---------------------------------------------------------------------------
// weight prepack: W fp32 [co][ci][9] -> Wp f16 [tap][co][ci], plus wsq.
// Coalesced: stage 2304 consecutive floats in LDS, then per-thread 9.
__global__ void k_packw(const float* __restrict__ w, f16* __restrict__ wp,
                        float* __restrict__ wsq) {
  __shared__ float buf[2304];
  int t = threadIdx.x;
  size_t base = (size_t)blockIdx.x * 2304;
  for (int i = t; i < 2304; i += 256) buf[i] = w[base + i];
  __syncthreads();
  int idx0 = blockIdx.x * 256;
  const float* src = buf + t * 9;
  float acc = 0.f;
#pragma unroll
  for (int tap = 0; tap < 9; ++tap) {
    float v = src[tap];
    wp[(size_t)tap * (C * C) + idx0 + t] = (f16)v;
    acc = fmaf(v, v, acc);
  }
  wsq[idx0 + t] = acc;
}

// ---------------------------------------------------------------------------
// demod: d[b][co] = rsqrt( sum_ci s[b][ci]^2 * wsq[co][ci] + eps )
__global__ void k_demod(const float* __restrict__ wsq,  // [C][C]
                        const float* __restrict__ s,    // [B][C]
                        float* __restrict__ dout) {     // [B][C]
  __shared__ float ssq[B * C];
  __shared__ float red[4][B];
  int co = blockIdx.x;
  int t = threadIdx.x;
  for (int idx = t; idx < B * C; idx += 256) {
    float v = s[idx];
    ssq[idx] = v * v;
  }
  __syncthreads();
  int ci0 = t * 2;
  float w0 = wsq[(size_t)co * C + ci0];
  float w1 = wsq[(size_t)co * C + ci0 + 1];
  float p[B];
#pragma unroll
  for (int b = 0; b < B; ++b) {
    p[b] = fmaf(ssq[b * C + ci0], w0, ssq[b * C + ci0 + 1] * w1);
  }
  int lane = t & 63, wv = t >> 6;
#pragma unroll
  for (int b = 0; b < B; ++b) {
    float v = p[b];
    for (int off = 32; off; off >>= 1) v += __shfl_down(v, off);
    if (lane == 0) red[wv][b] = v;
  }
  __syncthreads();
  if (t < B) {
    float tot = red[0][t] + red[1][t] + red[2][t] + red[3][t];
    dout[t * C + co] = rsqrtf(tot + EPS_D);
  }
}

// ---------------------------------------------------------------------------
__device__ __forceinline__ void up1d(int o, int& i0, int& i1, float& w0, float& w1) {
  float src = 0.5f * (float)o - 0.25f;
  float f = floorf(src);
  float fr = src - f;
  int i = (int)f;
  i0 = i < 0 ? 0 : i;
  int j = i + 1;
  i1 = j > (HIN - 1) ? (HIN - 1) : j;
  w1 = fr;
  w0 = 1.0f - fr;
}

// bilinear 2x upsample + s1 scale, NCHW fp32 -> NHWC f16.
__global__ __launch_bounds__(256) void k_up(const float* __restrict__ x,
                                            const float* __restrict__ s1,
                                            f16* __restrict__ xup) {
  __shared__ f16 xt[10 * 32 * 32];  // [(yl*32+x)*32 + ci]
  int bx = blockIdx.x;
  int b = bx >> 6;
  int ci0 = ((bx >> 2) & 15) * 32;
  int q = bx & 3;
  int ybase = q * 8 - 1;            // src rows ybase..ybase+9 (clamped)
  int t = threadIdx.x;
  int xi_ = t & 31, cl = t >> 5;    // cl 0..7
  for (int yl = 0; yl < 10; ++yl) {
    int y = ybase + yl;
    y = y < 0 ? 0 : (y > 31 ? 31 : y);
#pragma unroll
    for (int p = 0; p < 4; ++p) {
      int ci = p * 8 + cl;
      xt[(yl * 32 + xi_) * 32 + ci] =
          (f16)x[(((size_t)b * C + ci0 + ci) * 32 + y) * 32 + xi_];
    }
  }
  __syncthreads();
  int xo = t >> 2;          // 0..63
  int cg = (t & 3) * 8;
  float sv[8];
#pragma unroll
  for (int e = 0; e < 8; ++e) sv[e] = s1[b * C + ci0 + cg + e];
  int x0, x1; float wx0, wx1;
  up1d(xo, x0, x1, wx0, wx1);
  for (int yy = 0; yy < 16; ++yy) {
    int yo = q * 16 + yy;
    int y0, y1; float wy0, wy1;
    up1d(yo, y0, y1, wy0, wy1);
    int yl0 = y0 - ybase, yl1 = y1 - ybase;
    f16x8 t00 = *(const f16x8*)&xt[(yl0 * 32 + x0) * 32 + cg];
    f16x8 t01 = *(const f16x8*)&xt[(yl0 * 32 + x1) * 32 + cg];
    f16x8 t10 = *(const f16x8*)&xt[(yl1 * 32 + x0) * 32 + cg];
    f16x8 t11 = *(const f16x8*)&xt[(yl1 * 32 + x1) * 32 + cg];
    f16x8 o;
#pragma unroll
    for (int e = 0; e < 8; ++e) {
      float v = wy0 * (wx0 * (float)t00[e] + wx1 * (float)t01[e]) +
                wy1 * (wx0 * (float)t10[e] + wx1 * (float)t11[e]);
      o[e] = (f16)(v * sv[e]);
    }
    *(f16x8*)&xup[(((size_t)b * 64 + yo) * 64 + xo) * C + ci0 + cg] = o;
  }
}

// ---------------------------------------------------------------------------
// MFMA implicit-GEMM 3x3 conv. Block: 128 co x 256 px (4 rows x 64 cols),
// 4 waves; wave = 128co x 64px, acc 8x4 f32x4. K-chunk = 32 ci; weights
// staged 3 taps (one dy) at a time. K-major LDS with 24-dw region shift:
//   xs:   [c2(4)][pc(396)][16B]        region stride 6368B
//   wsm3: [dx*4+c2(12)][co(128)][16B]  region stride 2144B
// All fragment reads/writes <=2-way bank aliased (free). grid = 512 = 2/CU.
__global__ __launch_bounds__(256, 2) void k_conv_mfma(
    const f16* __restrict__ xin,      // [B][64][64][C]
    const f16* __restrict__ Wp,       // [9][C][C]
    const float* __restrict__ dmod,   // [B][C]
    const float* __restrict__ nscale, // [C]
    const float* __restrict__ noise,  // [B][HW]
    const float* __restrict__ s2v,    // [B][C] (conv1 only)
    f16* __restrict__ out_nhwc,       // conv1 out or null
    float* __restrict__ out_nchw) {   // conv2 out or null
  __shared__ char xsb[4 * XSS];       // 25472B
  __shared__ char wsb3[12 * WSS];     // 25728B

  int bx = blockIdx.x;
  int b = bx >> 6;
  int rem = bx & 63;
  int co_base = (rem >> 4) * 128;
  int y0 = (rem & 15) * 4;
  int t = threadIdx.x;
  int lane = t & 63, wid = t >> 6;
  int ln = lane & 15, kg = lane >> 4;

  f32x4 acc[8][4] = {};

  for (int ck = 0; ck < 16; ++ck) {
    for (int dyg = 0; dyg < 3; ++dyg) {
      __syncthreads();
      if (dyg == 0) {
        // stage input tile with halo: 6 rows x 66 cols x 32 ci (1584 chunks)
        for (int idx = t; idx < 1584; idx += 256) {
          int c2 = idx & 3;
          int pc = idx >> 2;             // 0..395
          int row = pc / 66, col = pc - row * 66;
          int gy = y0 + row - 1, gx = col - 1;
          f16x8 v = {};
          if ((unsigned)gy < 64u && (unsigned)gx < 64u)
            v = *(const f16x8*)&xin[(((size_t)b * 64 + gy) * 64 + gx) * C + ck * 32 + c2 * 8];
          *(f16x8*)(xsb + c2 * XSS + pc * 16) = v;
        }
      }
      // stage weights for 3 taps (dy = dyg, dx = 0..2): 1536 chunks, 6 iters
#pragma unroll
      for (int i = 0; i < 6; ++i) {
        int idx = i * 256 + t;
        int c2 = idx & 3;
        int co = (idx >> 2) & 127;
        int dx = idx >> 9;             // 0..2
        f16x8 v = *(const f16x8*)&Wp[((size_t)((dyg * 3 + dx) * C) + co_base + co) * C + ck * 32 + c2 * 8];
        *(f16x8*)(wsb3 + (dx * 4 + c2) * WSS + co * 16) = v;
      }
      __syncthreads();

#pragma unroll
      for (int dx = 0; dx < 3; ++dx) {
        f16x8 af[8], bf[4];
#pragma unroll
        for (int m = 0; m < 8; ++m)
          af[m] = *(const f16x8*)(wsb3 + (dx * 4 + kg) * WSS + (m * 16 + ln) * 16);
        int pcb = (wid + dyg) * 66 + ln + dx;
#pragma unroll
        for (int n = 0; n < 4; ++n)
          bf[n] = *(const f16x8*)(xsb + kg * XSS + (pcb + n * 16) * 16);
#pragma unroll
        for (int m = 0; m < 8; ++m)
#pragma unroll
          for (int n = 0; n < 4; ++n)
            acc[m][n] = __builtin_amdgcn_mfma_f32_16x16x32_f16(af[m], bf[n], acc[m][n], 0, 0, 0);
      }
    }
  }

  // epilogue
  int yo = y0 + wid;
  float nz[4];
#pragma unroll
  for (int n = 0; n < 4; ++n) nz[n] = noise[b * HW + yo * 64 + n * 16 + ln];

  if (out_nhwc) {
#pragma unroll
    for (int m = 0; m < 8; ++m) {
      int cog = co_base + m * 16 + kg * 4;
      f32x4 d4 = *(const f32x4*)&dmod[b * C + cog];
      f32x4 n4 = *(const f32x4*)&nscale[cog];
      f32x4 s4 = *(const f32x4*)&s2v[b * C + cog];
#pragma unroll
      for (int n = 0; n < 4; ++n) {
        int xo = n * 16 + ln;
        f16x4 o;
#pragma unroll
        for (int r = 0; r < 4; ++r) {
          float v = fmaf(acc[m][n][r], d4[r], n4[r] * nz[n]);
          v = v >= 0.f ? v : LRELU * v;
          o[r] = (f16)(v * s4[r]);
        }
        *(f16x4*)&out_nhwc[(((size_t)b * 64 + yo) * 64 + xo) * C + cog] = o;
      }
    }
  } else {
#pragma unroll
    for (int m = 0; m < 8; ++m) {
      int cog = co_base + m * 16 + kg * 4;
      f32x4 d4 = *(const f32x4*)&dmod[b * C + cog];
      f32x4 n4 = *(const f32x4*)&nscale[cog];
#pragma unroll
      for (int n = 0; n < 4; ++n) {
        int xo = n * 16 + ln;
#pragma unroll
        for (int r = 0; r < 4; ++r) {
          float v = fmaf(acc[m][n][r], d4[r], n4[r] * nz[n]);
          v = v >= 0.f ? v : LRELU * v;
          out_nchw[(((size_t)b * C + cog + r) * 64 + yo) * 64 + xo] = v;
        }
      }
    }
  }
}

// ---------------------------------------------------------------------------
// 1x1 toRGB, co-split: grid B*32 (128 px each), 256 threads.
// Thread halves handle co [0,256) and [256,512); LDS reduce, plain store.
__global__ void k_rgb(const float* __restrict__ h,    // [B][C][HW] fp32
                      const float* __restrict__ rw,   // [3][C]
                      const float* __restrict__ sr,   // [B][C]
                      float* __restrict__ rgb) {      // [B][3][HW]
  __shared__ float wsr[3][C];
  __shared__ float red[3][128];
  int bx = blockIdx.x;
  int b = bx >> 5;
  int chunk = bx & 31;
  int t = threadIdx.x;
  for (int idx = t; idx < 3 * C; idx += 256) {
    int c = idx >> 9, co = idx & 511;
    wsr[c][co] = rw[c * C + co] * sr[b * C + co];
  }
  __syncthreads();
  int px = chunk * 128 + (t & 127);
  int co0 = (t >> 7) * 256;
  float a0 = 0.f, a1 = 0.f, a2 = 0.f;
  const float* hp = h + ((size_t)b * C + co0) * HW + px;
#pragma unroll 4
  for (int co = 0; co < 256; ++co) {
    float hv = hp[(size_t)co * HW];
    a0 = fmaf(wsr[0][co0 + co], hv, a0);
    a1 = fmaf(wsr[1][co0 + co], hv, a1);
    a2 = fmaf(wsr[2][co0 + co], hv, a2);
  }
  if (t >= 128) {
    red[0][t - 128] = a0; red[1][t - 128] = a1; red[2][t - 128] = a2;
  }
  __syncthreads();
  if (t < 128) {
    float* rp = rgb + (size_t)b * 3 * HW + px;
    rp[0]      = a0 + red[0][t];
    rp[HW]     = a1 + red[1][t];
    rp[2 * HW] = a2 + red[2][t];
  }
}

// ---------------------------------------------------------------------------
extern "C" void kernel_launch(void* const* d_in, const int* in_sizes, int n_in,
                              void* d_out, int out_size, void* d_ws, size_t ws_size,
                              hipStream_t stream) {
  (void)in_sizes; (void)n_in; (void)out_size; (void)ws_size;
  const float* x   = (const float*)d_in[0];
  const float* wst = (const float*)d_in[1];
  const float* w1  = (const float*)d_in[2];
  const float* m1w = (const float*)d_in[3];
  const float* m1b = (const float*)d_in[4];
  const float* ns1 = (const float*)d_in[5];
  const float* w2  = (const float*)d_in[6];
  const float* m2w = (const float*)d_in[7];
  const float* m2b = (const float*)d_in[8];
  const float* ns2 = (const float*)d_in[9];
  const float* rw  = (const float*)d_in[10];
  const float* mrw = (const float*)d_in[11];
  const float* mrb = (const float*)d_in[12];
  const float* nz1 = (const float*)d_in[13];
  const float* nz2 = (const float*)d_in[14];

  char* wsb = (char*)d_ws;
  f16*   xup  = (f16*)(wsb + XUP_B);
  f16*   h1s  = (f16*)(wsb + H1S_B);
  f16*   wp1  = (f16*)(wsb + WP1_B);
  f16*   wp2  = (f16*)(wsb + WP2_B);
  float* s1   = (float*)(wsb + S1_B);
  float* s2   = (float*)(wsb + S2_B);
  float* srr  = (float*)(wsb + SR_B);
  float* dm1  = (float*)(wsb + D1_B);
  float* dm2  = (float*)(wsb + D2_B);
  float* wsq1 = (float*)(wsb + WSQ1_B);
  float* wsq2 = (float*)(wsb + WSQ2_B);

  float* hout   = (float*)d_out;                  // [B][C][HW]
  float* rgbout = hout + (size_t)B * C * HW;      // [B][3][HW]

  k_styles3<<<dim3(B, 3, 4), 256, 0, stream>>>(wst, m1w, m1b, s1, m2w, m2b, s2, mrw, mrb, srr);
  k_packw<<<C * C / 256, 256, 0, stream>>>(w1, wp1, wsq1);
  k_packw<<<C * C / 256, 256, 0, stream>>>(w2, wp2, wsq2);
  k_demod<<<C, 256, 0, stream>>>(wsq1, s1, dm1);
  k_demod<<<C, 256, 0, stream>>>(wsq2, s2, dm2);
  k_up<<<B * 64, 256, 0, stream>>>(x, s1, xup);
  k_conv_mfma<<<512, 256, 0, stream>>>(xup, wp1, dm1, ns1, nz1, s2, h1s, nullptr);
  k_conv_mfma<<<512, 256, 0, stream>>>(h1s, wp2, dm2, ns2, nz2, nullptr, nullptr, hout);
  k_rgb<<<B * 32, 256, 0, stream>>>(hout, rw, srr, rgbout);
}